// Round 6
// baseline (213.290 us; speedup 1.0000x reference)
//
#include <hip/hip_runtime.h>
#include <hip/hip_bf16.h>

#define V     8192
#define E_N   262144
#define NN    262144
#define D     128
#define KDIM  8192
#define SPLITK 4

typedef __attribute__((ext_vector_type(8))) short b16x8;
typedef __attribute__((ext_vector_type(4))) float f32x4;

static __device__ __forceinline__ unsigned short f2bf(float f) {
    union { float f; unsigned int u; } v; v.f = f;
    unsigned int r = v.u + 0x7FFFu + ((v.u >> 16) & 1u);   // RNE
    return (unsigned short)(r >> 16);
}

static __device__ __forceinline__ unsigned int cvtpk(float lo, float hi) {
    unsigned int r;
    asm("v_cvt_pk_bf16_f32 %0, %1, %2" : "=v"(r) : "v"(lo), "v"(hi));
    return r;
}

// ---- W [K][D] fp32 -> Wp[kb][c][kk] bf16 (kb=k>>5, kk=k&31); also zero cursor ----
__global__ void k_pack(const float* __restrict__ W, unsigned short* __restrict__ Wp,
                       int* __restrict__ cursor) {
    __shared__ float tile[32][129];
    int kb = blockIdx.x;            // 0..255
    int t  = threadIdx.x;           // 0..255
    if (kb < 32) cursor[kb * 256 + t] = 0;
    #pragma unroll
    for (int i = 0; i < 16; i++) {
        int lin = i * 256 + t;      // over (kk,c)
        int kk = lin >> 7, c = lin & 127;
        tile[kk][c] = W[(size_t)(kb * 32 + kk) * D + c];
    }
    __syncthreads();
    unsigned short* outp = Wp + (size_t)kb * 4096;
    #pragma unroll
    for (int i = 0; i < 16; i++) {
        int o = i * 256 + t;        // over (c,kk)
        int c = o >> 5, kk = o & 31;
        outp[o] = f2bf(tile[kk][c]);
    }
}

// ---- degree histogram over dst ----
__global__ void k_hist(const int* __restrict__ dst, int* __restrict__ hist) {
    int e = blockIdx.x * 256 + threadIdx.x;
    if (e < E_N) atomicAdd(&hist[dst[e]], 1);
}

// ---- exclusive scan of 8192 counts, single block ----
__global__ void k_scan(const int* __restrict__ hist, int* __restrict__ offsets,
                       int* __restrict__ cursor) {
    __shared__ int part[1024];
    int t = threadIdx.x;
    int base = t * 8;
    int loc[8]; int s = 0;
    for (int i = 0; i < 8; i++) { loc[i] = s; s += hist[base + i]; }
    part[t] = s;
    __syncthreads();
    for (int st = 1; st < 1024; st <<= 1) {
        int v = (t >= st) ? part[t - st] : 0;
        __syncthreads();
        part[t] += v;
        __syncthreads();
    }
    int ex = (t == 0) ? 0 : part[t - 1];
    for (int i = 0; i < 8; i++) {
        int o = ex + loc[i];
        offsets[base + i] = o;
        cursor[base + i] = o;
    }
    if (t == 1023) offsets[8192] = ex + s;
}

// ---- scatter edges into CSR-by-dst ----
__global__ void k_scatter(const int* __restrict__ srcI, const int* __restrict__ dstI,
                          const float* __restrict__ w, int* __restrict__ cursor,
                          int* __restrict__ src_s, float* __restrict__ w_s) {
    int e = blockIdx.x * 256 + threadIdx.x;
    if (e < E_N) {
        int dnode = dstI[e];
        int pos = atomicAdd(&cursor[dnode], 1);
        src_s[pos] = srcI[e];
        w_s[pos]  = w[e];
    }
}

// ---- Hp[ks] = A@W partial : copy-kernel A-stream, barrier-free ----
// BM=64, BK=256 floats. grid = 128 rb x 4 ks = 512 blocks (2/CU, 64 KB LDS).
// Wave w exclusively stages AND consumes rows w*16..w*16+15 -> no barriers,
// only per-wave vmcnt(0) once per step (8 steps).
// A staging: ONE global_load_lds per row = 64 lanes x 16 B = 1 KB CONTIGUOUS
// (identical pattern to the 6.3 TB/s copy kernel). Source 16-B slots XOR-
// swizzled by row&7 (dest linear, rule #21) so ds_read spreads banks.
// B fragments direct from L2 (Wp 2 MB), 2-deep prefetch, fully unrolled.
__global__ void __launch_bounds__(256, 2) k_gemm(const float* __restrict__ A,
                                                 const unsigned short* __restrict__ Wp,
                                                 float* __restrict__ Hp) {
    __shared__ float As[64][256];         // 64 KB single buffer

    const int rb  = blockIdx.x >> 2;      // 0..127
    const int ks  = blockIdx.x & 3;       // K slice of 2048
    const int tid = threadIdx.x;
    const int w   = tid >> 6;
    const int l   = tid & 63;
    const int r16 = l & 15;
    const int kg  = l >> 4;               // 0..3

    // row w*16 + r  (r&7 == (w*16+r)&7 since w*16 % 8 == 0)
    const float* aRow0 = A + (size_t)(rb * 64 + w * 16) * KDIM + ks * 2048;
    const unsigned short* bKS = Wp + (size_t)(ks * 64) * 4096 + r16 * 32 + kg * 8;

    f32x4 acc[8];
    f32x4 zero = {0.f, 0.f, 0.f, 0.f};
    #pragma unroll
    for (int t = 0; t < 8; t++) acc[t] = zero;

#define LDB(arr, stepBase, sub)                                                     \
    do { const unsigned short* bp_ = bKS + (size_t)((stepBase) + (sub)) * 4096;     \
         _Pragma("unroll")                                                          \
         for (int t = 0; t < 8; ++t) arr[t] = *(const b16x8*)(bp_ + t * 512);       \
    } while (0)

#define AFRAG(af, sub)                                                              \
    do { int g0 = (sub) * 8 + kg * 2;                                               \
         f32x4 x0 = *(const f32x4*)&As[w * 16 + r16][((g0)     ^ (r16 & 7)) << 2];  \
         f32x4 x1 = *(const f32x4*)&As[w * 16 + r16][((g0 + 1) ^ (r16 & 7)) << 2];  \
         af.u[0] = cvtpk(x0[0], x0[1]);  af.u[1] = cvtpk(x0[2], x0[3]);             \
         af.u[2] = cvtpk(x1[0], x1[1]);  af.u[3] = cvtpk(x1[2], x1[3]); } while (0)

#define MF(af, arr)                                                                 \
    do { _Pragma("unroll")                                                          \
         for (int t = 0; t < 8; ++t)                                                \
             acc[t] = __builtin_amdgcn_mfma_f32_16x16x32_bf16(af.v, arr[t],         \
                                                              acc[t], 0, 0, 0); } while (0)

#define SUB(s, CUR, NXT, stepBase)                                                  \
    do { if ((s) < 7) LDB(NXT, stepBase, (s) + 1);                                  \
         union { b16x8 v; unsigned int u[4]; } af_;                                 \
         AFRAG(af_, s);                                                             \
         MF(af_, CUR); } while (0)

    for (int step = 0; step < 8; ++step) {
        // ---- stage: 16 x 1-KB contiguous bursts (one per row), dest linear ----
        const float* aStep = aRow0 + step * 256;
        #pragma unroll
        for (int r = 0; r < 16; ++r) {
            __builtin_amdgcn_global_load_lds(
                (const __attribute__((address_space(1))) void*)
                    (aStep + (size_t)r * KDIM + ((l ^ (r & 7)) << 2)),
                (__attribute__((address_space(3))) void*)&As[w * 16 + r][0], 16, 0, 0);
        }

        b16x8 b0[8], b1[8];
        LDB(b0, step * 8, 0);                 // overlap first B with A wait

        asm volatile("s_waitcnt vmcnt(0)" ::: "memory");   // this wave's 16 KB landed

        SUB(0, b0, b1, step * 8);
        SUB(1, b1, b0, step * 8);
        SUB(2, b0, b1, step * 8);
        SUB(3, b1, b0, step * 8);
        SUB(4, b0, b1, step * 8);
        SUB(5, b1, b0, step * 8);
        SUB(6, b0, b1, step * 8);
        SUB(7, b1, b0, step * 8);
    }
#undef LDB
#undef AFRAG
#undef MF
#undef SUB

    // C/D map (16x16x32): col = r16 + t*16, row = kg*4 + j ; exclusive partial store
    float* hp = Hp + ((size_t)ks * V + (size_t)(rb * 64 + w * 16 + kg * 4)) * D + r16;
    #pragma unroll
    for (int t = 0; t < 8; t++)
        #pragma unroll
        for (int j = 0; j < 4; j++)
            hp[(size_t)j * D + t * 16] = acc[t][j];
}

// ---- H = b + sum_{ks} Hp[ks] ----
__global__ void k_comb(const float* __restrict__ Hp, const float* __restrict__ b,
                       float* __restrict__ H) {
    int i = blockIdx.x * 256 + threadIdx.x;        // over V*D/4
    f32x4 s = *(const f32x4*)(b + (i & 31) * 4);
    const f32x4* hp = (const f32x4*)Hp;
    const size_t q = (size_t)V * D / 4;
    #pragma unroll
    for (int k = 0; k < SPLITK; k++) s += hp[i + k * q];
    ((f32x4*)H)[i] = s;
}

// ---- emb = 0.8*P + 0.2*H, L2-normalize per row (V rows) ----
__global__ void k_emb(const float* __restrict__ H, const int* __restrict__ offsets,
                      const int* __restrict__ src_s, const float* __restrict__ w_s,
                      float* __restrict__ embn) {
    __shared__ float red[128];
    int v = blockIdx.x;
    int d = threadIdx.x;
    int s0 = offsets[v], s1 = offsets[v + 1];
    float acc = 0.f;
    for (int i = s0; i < s1; i++) {
        int s = src_s[i];
        float w = w_s[i];
        acc = fmaf(w, H[(size_t)s * D + d], acc);
    }
    float e = 0.8f * acc + 0.2f * H[(size_t)v * D + d];
    red[d] = e * e;
    __syncthreads();
    for (int st = 64; st > 0; st >>= 1) {
        if (d < st) red[d] += red[d + st];
        __syncthreads();
    }
    float norm = sqrtf(red[0]);
    float scale = 1.f / fmaxf(norm, 1e-12f);
    embn[(size_t)v * D + d] = e * scale;
}

// ---- out[n] = embn[x[n]] ----
__global__ void k_out(const int* __restrict__ x, const float* __restrict__ embn,
                      float* __restrict__ out) {
    int t = blockIdx.x * 256 + threadIdx.x;   // over NN * 32
    int n = t >> 5, c = t & 31;
    int xv = x[n];
    ((f32x4*)out)[t] = ((const f32x4*)embn)[xv * 32 + c];
}

extern "C" void kernel_launch(void* const* d_in, const int* in_sizes, int n_in,
                              void* d_out, int out_size, void* d_ws, size_t ws_size,
                              hipStream_t stream) {
    const int*   x      = (const int*)d_in[0];
    const int*   eSrc   = (const int*)d_in[1];          // edge_index[0]
    const int*   eDst   = ((const int*)d_in[1]) + E_N;  // edge_index[1]
    const float* eW     = (const float*)d_in[2];
    const float* A      = (const float*)d_in[3];        // embedding [V][V]
    const float* W      = (const float*)d_in[4];        // [V][D]
    const float* b      = (const float*)d_in[5];        // [D]
    float* out = (float*)d_out;

    char* ws = (char*)d_ws;
    unsigned short* Wp  = (unsigned short*)(ws);                        // 2 MB
    float* H            = (float*)(ws + (2u << 20));                    // 4 MB
    float* embn         = (float*)(ws + (6u << 20));                    // 4 MB
    float* Hp           = (float*)(ws + (10u << 20));                   // 16 MB (4 partials)
    int* offsets        = (int*)(ws + (26u << 20));                     // 8193 ints
    int* cursor         = (int*)(ws + (26u << 20) + 40960);             // 8192 ints (also hist)
    int* src_s          = (int*)(ws + (26u << 20) + 131072);            // 1 MB
    float* w_s          = (float*)(ws + (26u << 20) + 131072 + (1u << 20)); // 1 MB

    k_pack   <<<256, 256, 0, stream>>>(W, Wp, cursor);
    k_hist   <<<E_N / 256, 256, 0, stream>>>(eDst, cursor);
    k_scan   <<<1, 1024, 0, stream>>>(cursor, offsets, cursor);
    k_scatter<<<E_N / 256, 256, 0, stream>>>(eSrc, eDst, eW, cursor, src_s, w_s);
    k_gemm   <<<512, 256, 0, stream>>>(A, Wp, Hp);
    k_comb   <<<(V * D / 4) / 256, 256, 0, stream>>>(Hp, b, H);
    k_emb    <<<V, D, 0, stream>>>(H, offsets, src_s, w_s, embn);
    k_out    <<<(NN * 32) / 256, 256, 0, stream>>>(x, embn, out);
}